// Round 1
// baseline (392.179 us; speedup 1.0000x reference)
//
#include <hip/hip_runtime.h>

typedef unsigned int u32;
typedef unsigned short u16;
typedef short s16x8 __attribute__((ext_vector_type(8)));
typedef float f32x4 __attribute__((ext_vector_type(4)));

#define MFMA16(a,b,c) __builtin_amdgcn_mfma_f32_16x16x32_bf16((a),(b),(c),0,0,0)

#define Bb 8
#define Hh 16
#define Qq 128
#define HDd 128
#define Dd 2048
#define CACHE 3968
#define SCALE 0.08838834764831845f   // 1/sqrt(128)

__device__ __forceinline__ u16 f2bf(float x){
  u32 u = __builtin_bit_cast(u32, x);
  u32 r = ((u >> 16) & 1u) + 0x7fffu;
  return (u16)((u + r) >> 16);
}
__device__ __forceinline__ float bf2f(u16 h){
  return __builtin_bit_cast(float, ((u32)h) << 16);
}
__device__ __forceinline__ u32 pk2(float a, float b){
  return (u32)f2bf(a) | ((u32)f2bf(b) << 16);
}
__device__ __forceinline__ float f4c(const float4& v, int j){
  return j==0 ? v.x : j==1 ? v.y : j==2 ? v.z : v.w;
}
__device__ __forceinline__ void gload_lds16(const void* g, void* l){
  __builtin_amdgcn_global_load_lds(
      (const __attribute__((address_space(1))) u32*)g,
      (__attribute__((address_space(3))) u32*)l, 16, 0, 0);
}

// ---------------- elementwise f32 -> bf16 ----------------
__global__ void k_cvt(const float* __restrict__ s, u16* __restrict__ d, int n4){
  int i = blockIdx.x * 256 + threadIdx.x;
  if (i < n4){
    float4 v = *(const float4*)(s + (size_t)i * 4);
    *(uint2*)(d + (size_t)i * 4) = make_uint2(pk2(v.x, v.y), pk2(v.z, v.w));
  }
}

// ---------------- transpose + convert: src[R][C] f32 -> dst[C][R] bf16 ----------------
__global__ void k_tcvt(const float* __restrict__ s, u16* __restrict__ d, int R, int C){
  __shared__ float t[32][33];
  int tx = threadIdx.x & 31, ty = threadIdx.x >> 5;
  int c0 = blockIdx.x * 32, r0 = blockIdx.y * 32;
#pragma unroll
  for (int i = 0; i < 4; i++)
    t[ty + i*8][tx] = s[(size_t)(r0 + ty + i*8) * C + c0 + tx];
  __syncthreads();
#pragma unroll
  for (int i = 0; i < 4; i++)
    d[(size_t)(c0 + ty + i*8) * R + r0 + tx] = f2bf(t[tx][ty + i*8]);
}

// ---------------- GEMM: C[M][N] = A[M][K] * Bt[N][K]^T ----------------
// 128x128 tile, BK=32, 256 threads (4 waves, 2x2), double-buffered global_load_lds.
// MODE 0: scatter to q/k/v ws (bf16, q scaled). MODE 1: fp32 out + bias.
template<int MODE>
__global__ __launch_bounds__(256)
void k_gemm(const u16* __restrict__ A, const u16* __restrict__ Bt, int K, int N,
            u16* __restrict__ oq, u16* __restrict__ ok, u16* __restrict__ ov,
            float* __restrict__ of, const float* __restrict__ bias)
{
  const int m0 = blockIdx.y * 128, n0 = blockIdx.x * 128;
  const int tid = threadIdx.x;
  const int w = tid >> 6, l = tid & 63;
  const int lg = l >> 4, lr = l & 15;
  const int wr = w >> 1, wc = w & 1;

  __shared__ u16 As[2][128 * 32];
  __shared__ u16 Bs[2][128 * 32];

  f32x4 acc[4][4];
#pragma unroll
  for (int i = 0; i < 4; i++)
#pragma unroll
    for (int j = 0; j < 4; j++) acc[i][j] = f32x4{0.f, 0.f, 0.f, 0.f};

  const int nt = K >> 5;

  auto stage = [&](int buf, int t){
    const int k0 = t << 5;
#pragma unroll
    for (int i = 0; i < 2; i++){
      int flat = i * 256 + tid;          // 0..511
      int row = flat >> 2, kq = flat & 3;
      const u16* ga = A + (size_t)(m0 + row) * K + k0 + kq * 8;
      gload_lds16(ga, (char*)&As[buf][0] + (size_t)(i*256 + w*64) * 16);
      const u16* gb = Bt + (size_t)(n0 + row) * K + k0 + kq * 8;
      gload_lds16(gb, (char*)&Bs[buf][0] + (size_t)(i*256 + w*64) * 16);
    }
  };

  stage(0, 0);
  asm volatile("s_waitcnt vmcnt(0)" ::: "memory");
  __syncthreads();

  for (int t = 0; t < nt; ++t){
    const int buf = t & 1;
    if (t + 1 < nt) stage(buf ^ 1, t + 1);
    s16x8 af[4], bfr[4];
#pragma unroll
    for (int i = 0; i < 4; i++){
      int row = wr*64 + i*16 + lr;
      af[i] = *(const s16x8*)&As[buf][row*32 + lg*8];
    }
#pragma unroll
    for (int j = 0; j < 4; j++){
      int col = wc*64 + j*16 + lr;
      bfr[j] = *(const s16x8*)&Bs[buf][col*32 + lg*8];
    }
#pragma unroll
    for (int i = 0; i < 4; i++)
#pragma unroll
      for (int j = 0; j < 4; j++)
        acc[i][j] = MFMA16(af[i], bfr[j], acc[i][j]);
    asm volatile("s_waitcnt vmcnt(0)" ::: "memory");
    __syncthreads();
  }

#pragma unroll
  for (int i = 0; i < 4; i++){
#pragma unroll
    for (int j = 0; j < 4; j++){
#pragma unroll
      for (int r = 0; r < 4; r++){
        int m = m0 + wr*64 + i*16 + lg*4 + r;
        int n = n0 + wc*64 + j*16 + lr;
        float v = acc[i][j][r];
        if (MODE == 0){
          int which = n >> 11;
          int h = (n >> 7) & 15, hd = n & 127;
          int b = m >> 7, qi = m & 127;
          size_t idx = (((size_t)(b * Hh + h)) * Qq + qi) * HDd + hd;
          if (which == 0)      oq[idx] = f2bf(v * SCALE);
          else if (which == 1) ok[idx] = f2bf(v);
          else                 ov[idx] = f2bf(v);
        } else {
          of[(size_t)m * N + n] = v + bias[n];
        }
      }
    }
  }
}

// ---------------- fused cached attention ----------------
// grid = B*H = 128 blocks, 512 threads (8 waves x 16 q-rows), KV chunk = 64.
__global__ __launch_bounds__(512)
void k_attn(const float* __restrict__ kc, const float* __restrict__ vc,
            const u16* __restrict__ qw, const u16* __restrict__ knw,
            const u16* __restrict__ vnw, u16* __restrict__ ao)
{
  const int bh = blockIdx.x;
  const int tid = threadIdx.x;
  const int w = tid >> 6, l = tid & 63;
  const int lg = l >> 4, lr = l & 15;

  __shared__ u16 Ks[64 * 136];   // row-major [key][hd], pitch 136 (pad 8)
  __shared__ u32 Vts[128 * 32];  // transposed, pair-packed, 16B-XOR swizzled
  __shared__ u16 Pl[8 * 16 * 72];// per-wave P, pitch 72

  // Q fragments (pre-scaled by GEMM epilogue): rows w*16 + lr
  s16x8 qf[4];
  {
    const u16* qp = qw + (((size_t)bh * Qq + w*16 + lr) * HDd);
#pragma unroll
    for (int kk = 0; kk < 4; kk++) qf[kk] = *(const s16x8*)(qp + kk*32 + lg*8);
  }

  f32x4 acc[8];
#pragma unroll
  for (int i = 0; i < 8; i++) acc[i] = f32x4{0.f, 0.f, 0.f, 0.f};
  float mrow[4], lsum[4];
#pragma unroll
  for (int r = 0; r < 4; r++){ mrow[r] = -__builtin_inff(); lsum[r] = 0.f; }

  const float* kbase = kc + (size_t)bh * CACHE * HDd;
  const float* vbase = vc + (size_t)bh * CACHE * HDd;
  const u16* knb = knw + (size_t)bh * Qq * HDd;
  const u16* vnb = vnw + (size_t)bh * Qq * HDd;

  const int rv = tid & 15, c4v = tid >> 4;   // V-staging assignment

  float4 kreg[4], vreg[4];

  auto loadc = [&](int c){
    if (c < 62){
#pragma unroll
      for (int i = 0; i < 4; i++){
        int flat = tid + i*512;
        int row = flat >> 5, c4 = flat & 31;
        kreg[i] = *(const float4*)(kbase + ((size_t)(c*64 + row)) * HDd + c4*4);
      }
#pragma unroll
      for (int a = 0; a < 4; a++)
        vreg[a] = *(const float4*)(vbase + ((size_t)(c*64 + rv + a*16)) * HDd + c4v*4);
    } else {
#pragma unroll
      for (int i = 0; i < 4; i++){
        int flat = tid + i*512;
        int row = flat >> 5, c4 = flat & 31;
        ushort4 u = *(const ushort4*)(knb + ((size_t)(c*64 + row - CACHE)) * HDd + c4*4);
        kreg[i] = make_float4(bf2f(u.x), bf2f(u.y), bf2f(u.z), bf2f(u.w));
      }
#pragma unroll
      for (int a = 0; a < 4; a++){
        ushort4 u = *(const ushort4*)(vnb + ((size_t)(c*64 + rv + a*16 - CACHE)) * HDd + c4v*4);
        vreg[a] = make_float4(bf2f(u.x), bf2f(u.y), bf2f(u.z), bf2f(u.w));
      }
    }
  };

  loadc(0);

  for (int c = 0; c < 64; ++c){
    // ---- write staged regs -> LDS (cvt to bf16) ----
#pragma unroll
    for (int i = 0; i < 4; i++){
      int flat = tid + i*512;
      int row = flat >> 5, c4 = flat & 31;
      *(uint2*)&Ks[row*136 + c4*4] =
          make_uint2(pk2(kreg[i].x, kreg[i].y), pk2(kreg[i].z, kreg[i].w));
    }
#pragma unroll
    for (int j = 0; j < 4; j++){
      int col = c4v*4 + j;
      int x2 = (col & 7) << 2;
      // key-position permutation: pos 2r<-key r, 2r+1<-key r+16, 32+2r<-key r+32, 33+2r<-key r+48
      Vts[col*32 + (rv ^ x2)]        = pk2(f4c(vreg[0], j), f4c(vreg[1], j));
      Vts[col*32 + ((rv + 16) ^ x2)] = pk2(f4c(vreg[2], j), f4c(vreg[3], j));
    }
    __syncthreads();
    if (c + 1 < 64) loadc(c + 1);   // async-stage next chunk under compute

    // ---- QK^T : S[16 q][64 key] per wave ----
    f32x4 s[4];
#pragma unroll
    for (int t = 0; t < 4; t++){
      s[t] = f32x4{0.f, 0.f, 0.f, 0.f};
      const u16* kp = &Ks[(t*16 + lr) * 136];
#pragma unroll
      for (int kk = 0; kk < 4; kk++){
        s16x8 kf = *(const s16x8*)(kp + kk*32 + lg*8);
        s[t] = MFMA16(qf[kk], kf, s[t]);
      }
    }
    // ---- causal mask (only last two chunks) ----
    if (c >= 62){
      int jn = c*64 - CACHE;
#pragma unroll
      for (int t = 0; t < 4; t++){
        int kn = jn + t*16 + lr;
#pragma unroll
        for (int r = 0; r < 4; r++){
          int qi = w*16 + lg*4 + r;
          if (kn > qi) s[t][r] = -__builtin_inff();
        }
      }
    }
    // ---- online softmax ----
    float corr[4];
#pragma unroll
    for (int r = 0; r < 4; r++){
      float v = fmaxf(fmaxf(s[0][r], s[1][r]), fmaxf(s[2][r], s[3][r]));
      v = fmaxf(v, __shfl_xor(v, 1));
      v = fmaxf(v, __shfl_xor(v, 2));
      v = fmaxf(v, __shfl_xor(v, 4));
      v = fmaxf(v, __shfl_xor(v, 8));
      float mn = fmaxf(mrow[r], v);
      corr[r] = __expf(mrow[r] - mn);
      mrow[r] = mn;
    }
    float ps[4] = {0.f, 0.f, 0.f, 0.f};
#pragma unroll
    for (int t = 0; t < 4; t++)
#pragma unroll
      for (int r = 0; r < 4; r++){
        float p = __expf(s[t][r] - mrow[r]);
        s[t][r] = p;
        ps[r] += p;
      }
#pragma unroll
    for (int r = 0; r < 4; r++){
      float v = ps[r];
      v += __shfl_xor(v, 1);
      v += __shfl_xor(v, 2);
      v += __shfl_xor(v, 4);
      v += __shfl_xor(v, 8);
      lsum[r] = lsum[r] * corr[r] + v;
    }
#pragma unroll
    for (int i = 0; i < 8; i++)
#pragma unroll
      for (int r = 0; r < 4; r++) acc[i][r] *= corr[r];

    // ---- P -> LDS (permuted columns matching V positions) ----
    u16* pw = &Pl[w * 16 * 72];
#pragma unroll
    for (int t = 0; t < 4; t++){
      int pos = ((t >> 1) << 5) + 2*lr + (t & 1);
#pragma unroll
      for (int r = 0; r < 4; r++)
        pw[(lg*4 + r) * 72 + pos] = f2bf(s[t][r]);
    }
    s16x8 pf[2];
#pragma unroll
    for (int kk = 0; kk < 2; kk++)
      pf[kk] = *(const s16x8*)(pw + lr*72 + kk*32 + lg*8);

    // ---- PV : acc[8 hd-tiles] ----
#pragma unroll
    for (int t = 0; t < 8; t++){
      int col = t*16 + lr;
      const u32* vp = &Vts[col * 32];
#pragma unroll
      for (int kk = 0; kk < 2; kk++){
        s16x8 vf = *(const s16x8*)(vp + ((16*kk + 4*lg) ^ ((col & 7) << 2)));
        acc[t] = MFMA16(pf[kk], vf, acc[t]);
      }
    }
    __syncthreads();
  }

  // ---- epilogue: [B][Q][H*HD] bf16 ----
  u16* aop = ao + ((size_t)(bh >> 4)) * Qq * Dd + (size_t)(bh & 15) * HDd;
#pragma unroll
  for (int t = 0; t < 8; t++){
#pragma unroll
    for (int r = 0; r < 4; r++){
      int qi = w*16 + lg*4 + r;
      aop[(size_t)qi * Dd + t*16 + lr] = f2bf(acc[t][r] / lsum[r]);
    }
  }
}

extern "C" void kernel_launch(void* const* d_in, const int* in_sizes, int n_in,
                              void* d_out, int out_size, void* d_ws, size_t ws_size,
                              hipStream_t stream)
{
  const float* x     = (const float*)d_in[0];
  const float* kc    = (const float*)d_in[1];
  const float* vc    = (const float*)d_in[2];
  const float* wqkv  = (const float*)d_in[3];
  const float* wproj = (const float*)d_in[4];
  const float* bproj = (const float*)d_in[5];
  float* out = (float*)d_out;

  char* ws = (char*)d_ws;
  u16* xb  = (u16*)(ws);                      // 4 MB : x bf16 [1024][2048]
  u16* wtq = (u16*)(ws + ((size_t)4  << 20)); // 24 MB: Wqkv^T bf16 [6144][2048]
  u16* wtp = (u16*)(ws + ((size_t)28 << 20)); // 8 MB : Wproj^T bf16 [2048][2048]
  u16* qw  = (u16*)(ws + ((size_t)36 << 20)); // 4 MB : q (scaled) [B][H][Q][HD]
  u16* knw = (u16*)(ws + ((size_t)40 << 20)); // 4 MB : k_new
  u16* vnw = (u16*)(ws + ((size_t)44 << 20)); // 4 MB : v_new
  u16* aow = (u16*)(ws + ((size_t)48 << 20)); // 4 MB : attn out [1024][2048]

  k_cvt<<<2048, 256, 0, stream>>>(x, xb, (1024 * 2048) / 4);
  k_tcvt<<<dim3(192, 64), 256, 0, stream>>>(wqkv, wtq, 2048, 6144);
  k_tcvt<<<dim3(64, 64), 256, 0, stream>>>(wproj, wtp, 2048, 2048);
  k_gemm<0><<<dim3(48, 8), 256, 0, stream>>>(xb, wtq, 2048, 6144,
                                             qw, knw, vnw, nullptr, nullptr);
  k_attn<<<128, 512, 0, stream>>>(kc, vc, qw, knw, vnw, aow);
  k_gemm<1><<<dim3(16, 8), 256, 0, stream>>>(aow, wtp, 2048, 2048,
                                             nullptr, nullptr, nullptr, out, bproj);
}

// Round 2
// 304.875 us; speedup vs baseline: 1.2864x; 1.2864x over previous
//
#include <hip/hip_runtime.h>

typedef unsigned int u32;
typedef unsigned short u16;
typedef short s16x8 __attribute__((ext_vector_type(8)));
typedef float f32x4 __attribute__((ext_vector_type(4)));

#define MFMA16(a,b,c) __builtin_amdgcn_mfma_f32_16x16x32_bf16((a),(b),(c),0,0,0)

#define Bb 8
#define Hh 16
#define Qq 128
#define HDd 128
#define Dd 2048
#define CACHE 3968
#define NSPLIT 8            // KV segments per head (512 keys each)
#define SCALE 0.08838834764831845f   // 1/sqrt(128)

__device__ __forceinline__ u16 f2bf(float x){
  u32 u = __builtin_bit_cast(u32, x);
  u32 r = ((u >> 16) & 1u) + 0x7fffu;
  return (u16)((u + r) >> 16);
}
__device__ __forceinline__ float bf2f(u16 h){
  return __builtin_bit_cast(float, ((u32)h) << 16);
}
__device__ __forceinline__ u32 pk2(float a, float b){
  return (u32)f2bf(a) | ((u32)f2bf(b) << 16);
}
__device__ __forceinline__ float f4c(const float4& v, int j){
  return j==0 ? v.x : j==1 ? v.y : j==2 ? v.z : v.w;
}
__device__ __forceinline__ void gload_lds16(const void* g, void* l){
  __builtin_amdgcn_global_load_lds(
      (const __attribute__((address_space(1))) u32*)g,
      (__attribute__((address_space(3))) u32*)l, 16, 0, 0);
}

// ---------------- elementwise f32 -> bf16 ----------------
__global__ void k_cvt(const float* __restrict__ s, u16* __restrict__ d, int n4){
  int i = blockIdx.x * 256 + threadIdx.x;
  if (i < n4){
    float4 v = *(const float4*)(s + (size_t)i * 4);
    *(uint2*)(d + (size_t)i * 4) = make_uint2(pk2(v.x, v.y), pk2(v.z, v.w));
  }
}

// ---------------- transpose + convert: src[R][C] f32 -> dst[C][R] bf16 ----------------
__global__ void k_tcvt(const float* __restrict__ s, u16* __restrict__ d, int R, int C){
  __shared__ float t[32][33];
  int tx = threadIdx.x & 31, ty = threadIdx.x >> 5;
  int c0 = blockIdx.x * 32, r0 = blockIdx.y * 32;
#pragma unroll
  for (int i = 0; i < 4; i++)
    t[ty + i*8][tx] = s[(size_t)(r0 + ty + i*8) * C + c0 + tx];
  __syncthreads();
#pragma unroll
  for (int i = 0; i < 4; i++)
    d[(size_t)(c0 + ty + i*8) * R + r0 + tx] = f2bf(t[tx][ty + i*8]);
}

// ---------------- GEMM: C[M][N] = A[M][K] * Bt[N][K]^T ----------------
// 128x128 tile, BK=32, 256 threads (4 waves, 2x2), double-buffered global_load_lds.
// MODE 0: scatter to q/k/v ws (bf16, q scaled). MODE 1: fp32 out + bias.
template<int MODE>
__global__ __launch_bounds__(256)
void k_gemm(const u16* __restrict__ A, const u16* __restrict__ Bt, int K, int N,
            u16* __restrict__ oq, u16* __restrict__ ok, u16* __restrict__ ov,
            float* __restrict__ of, const float* __restrict__ bias)
{
  const int m0 = blockIdx.y * 128, n0 = blockIdx.x * 128;
  const int tid = threadIdx.x;
  const int w = tid >> 6, l = tid & 63;
  const int lg = l >> 4, lr = l & 15;
  const int wr = w >> 1, wc = w & 1;

  __shared__ u16 As[2][128 * 32];
  __shared__ u16 Bs[2][128 * 32];

  f32x4 acc[4][4];
#pragma unroll
  for (int i = 0; i < 4; i++)
#pragma unroll
    for (int j = 0; j < 4; j++) acc[i][j] = f32x4{0.f, 0.f, 0.f, 0.f};

  const int nt = K >> 5;

  auto stage = [&](int buf, int t){
    const int k0 = t << 5;
#pragma unroll
    for (int i = 0; i < 2; i++){
      int flat = i * 256 + tid;          // 0..511
      int row = flat >> 2, kq = flat & 3;
      const u16* ga = A + (size_t)(m0 + row) * K + k0 + kq * 8;
      gload_lds16(ga, (char*)&As[buf][0] + (size_t)(i*256 + w*64) * 16);
      const u16* gb = Bt + (size_t)(n0 + row) * K + k0 + kq * 8;
      gload_lds16(gb, (char*)&Bs[buf][0] + (size_t)(i*256 + w*64) * 16);
    }
  };

  stage(0, 0);
  asm volatile("s_waitcnt vmcnt(0)" ::: "memory");
  __syncthreads();

  for (int t = 0; t < nt; ++t){
    const int buf = t & 1;
    if (t + 1 < nt) stage(buf ^ 1, t + 1);
    s16x8 af[4], bfr[4];
#pragma unroll
    for (int i = 0; i < 4; i++){
      int row = wr*64 + i*16 + lr;
      af[i] = *(const s16x8*)&As[buf][row*32 + lg*8];
    }
#pragma unroll
    for (int j = 0; j < 4; j++){
      int col = wc*64 + j*16 + lr;
      bfr[j] = *(const s16x8*)&Bs[buf][col*32 + lg*8];
    }
#pragma unroll
    for (int i = 0; i < 4; i++)
#pragma unroll
      for (int j = 0; j < 4; j++)
        acc[i][j] = MFMA16(af[i], bfr[j], acc[i][j]);
    asm volatile("s_waitcnt vmcnt(0)" ::: "memory");
    __syncthreads();
  }

#pragma unroll
  for (int i = 0; i < 4; i++){
#pragma unroll
    for (int j = 0; j < 4; j++){
#pragma unroll
      for (int r = 0; r < 4; r++){
        int m = m0 + wr*64 + i*16 + lg*4 + r;
        int n = n0 + wc*64 + j*16 + lr;
        float v = acc[i][j][r];
        if (MODE == 0){
          int which = n >> 11;
          int h = (n >> 7) & 15, hd = n & 127;
          int b = m >> 7, qi = m & 127;
          size_t idx = (((size_t)(b * Hh + h)) * Qq + qi) * HDd + hd;
          if (which == 0)      oq[idx] = f2bf(v * SCALE);
          else if (which == 1) ok[idx] = f2bf(v);
          else                 ov[idx] = f2bf(v);
        } else {
          of[(size_t)m * N + n] = v + bias[n];
        }
      }
    }
  }
}

// ---------------- fused cached attention, split-KV (flash-decode) ----------------
// grid = B*H*NSPLIT = 1024 blocks, 512 threads (8 waves x 16 q-rows), chunk = 64 keys,
// 8 chunks per block. Emits unnormalized partial O (fp32) + per-row (m, l).
__global__ __launch_bounds__(512)
void k_attn(const float* __restrict__ kc, const float* __restrict__ vc,
            const u16* __restrict__ qw, const u16* __restrict__ knw,
            const u16* __restrict__ vnw, float* __restrict__ opart,
            float2* __restrict__ ml)
{
  const int bh = blockIdx.x >> 3;          // head index
  const int sg = blockIdx.x & 7;           // KV segment
  const int tid = threadIdx.x;
  const int w = tid >> 6, l = tid & 63;
  const int lg = l >> 4, lr = l & 15;

  __shared__ u16 Ks[64 * 136];   // row-major [key][hd], pitch 136 (pad 8)
  __shared__ u32 Vts[128 * 32];  // transposed, pair-packed, 16B-XOR swizzled
  __shared__ u16 Pl[8 * 16 * 72];// per-wave P, pitch 72

  // Q fragments (pre-scaled by GEMM epilogue): rows w*16 + lr
  s16x8 qf[4];
  {
    const u16* qp = qw + (((size_t)bh * Qq + w*16 + lr) * HDd);
#pragma unroll
    for (int kk = 0; kk < 4; kk++) qf[kk] = *(const s16x8*)(qp + kk*32 + lg*8);
  }

  f32x4 acc[8];
#pragma unroll
  for (int i = 0; i < 8; i++) acc[i] = f32x4{0.f, 0.f, 0.f, 0.f};
  float mrow[4], lsum[4];
#pragma unroll
  for (int r = 0; r < 4; r++){ mrow[r] = -__builtin_inff(); lsum[r] = 0.f; }

  const float* kbase = kc + (size_t)bh * CACHE * HDd;
  const float* vbase = vc + (size_t)bh * CACHE * HDd;
  const u16* knb = knw + (size_t)bh * Qq * HDd;
  const u16* vnb = vnw + (size_t)bh * Qq * HDd;

  const int rv = tid & 15, c4v = tid >> 4;   // V-staging assignment

  float4 kreg[4], vreg[4];

  auto loadc = [&](int c){        // c = GLOBAL chunk index (0..63)
    if (c < 62){
#pragma unroll
      for (int i = 0; i < 4; i++){
        int flat = tid + i*512;
        int row = flat >> 5, c4 = flat & 31;
        kreg[i] = *(const float4*)(kbase + ((size_t)(c*64 + row)) * HDd + c4*4);
      }
#pragma unroll
      for (int a = 0; a < 4; a++)
        vreg[a] = *(const float4*)(vbase + ((size_t)(c*64 + rv + a*16)) * HDd + c4v*4);
    } else {
#pragma unroll
      for (int i = 0; i < 4; i++){
        int flat = tid + i*512;
        int row = flat >> 5, c4 = flat & 31;
        ushort4 u = *(const ushort4*)(knb + ((size_t)(c*64 + row - CACHE)) * HDd + c4*4);
        kreg[i] = make_float4(bf2f(u.x), bf2f(u.y), bf2f(u.z), bf2f(u.w));
      }
#pragma unroll
      for (int a = 0; a < 4; a++){
        ushort4 u = *(const ushort4*)(vnb + ((size_t)(c*64 + rv + a*16 - CACHE)) * HDd + c4v*4);
        vreg[a] = make_float4(bf2f(u.x), bf2f(u.y), bf2f(u.z), bf2f(u.w));
      }
    }
  };

  loadc(sg * 8);

  for (int cl = 0; cl < 8; ++cl){
    const int c = sg * 8 + cl;     // global chunk
    // ---- write staged regs -> LDS (cvt to bf16) ----
#pragma unroll
    for (int i = 0; i < 4; i++){
      int flat = tid + i*512;
      int row = flat >> 5, c4 = flat & 31;
      *(uint2*)&Ks[row*136 + c4*4] =
          make_uint2(pk2(kreg[i].x, kreg[i].y), pk2(kreg[i].z, kreg[i].w));
    }
#pragma unroll
    for (int j = 0; j < 4; j++){
      int col = c4v*4 + j;
      int x2 = (col & 7) << 2;
      Vts[col*32 + (rv ^ x2)]        = pk2(f4c(vreg[0], j), f4c(vreg[1], j));
      Vts[col*32 + ((rv + 16) ^ x2)] = pk2(f4c(vreg[2], j), f4c(vreg[3], j));
    }
    __syncthreads();
    if (cl + 1 < 8) loadc(c + 1);   // async-stage next chunk under compute

    // ---- QK^T : S[16 q][64 key] per wave ----
    f32x4 s[4];
#pragma unroll
    for (int t = 0; t < 4; t++){
      s[t] = f32x4{0.f, 0.f, 0.f, 0.f};
      const u16* kp = &Ks[(t*16 + lr) * 136];
#pragma unroll
      for (int kk = 0; kk < 4; kk++){
        s16x8 kf = *(const s16x8*)(kp + kk*32 + lg*8);
        s[t] = MFMA16(qf[kk], kf, s[t]);
      }
    }
    // ---- causal mask (only last two global chunks) ----
    if (c >= 62){
      int jn = c*64 - CACHE;
#pragma unroll
      for (int t = 0; t < 4; t++){
        int kn = jn + t*16 + lr;
#pragma unroll
        for (int r = 0; r < 4; r++){
          int qi = w*16 + lg*4 + r;
          if (kn > qi) s[t][r] = -__builtin_inff();
        }
      }
    }
    // ---- online softmax ----
    float corr[4];
#pragma unroll
    for (int r = 0; r < 4; r++){
      float v = fmaxf(fmaxf(s[0][r], s[1][r]), fmaxf(s[2][r], s[3][r]));
      v = fmaxf(v, __shfl_xor(v, 1));
      v = fmaxf(v, __shfl_xor(v, 2));
      v = fmaxf(v, __shfl_xor(v, 4));
      v = fmaxf(v, __shfl_xor(v, 8));
      float mn = fmaxf(mrow[r], v);
      corr[r] = __expf(mrow[r] - mn);
      mrow[r] = mn;
    }
    float ps[4] = {0.f, 0.f, 0.f, 0.f};
#pragma unroll
    for (int t = 0; t < 4; t++)
#pragma unroll
      for (int r = 0; r < 4; r++){
        float p = __expf(s[t][r] - mrow[r]);
        s[t][r] = p;
        ps[r] += p;
      }
#pragma unroll
    for (int r = 0; r < 4; r++){
      float v = ps[r];
      v += __shfl_xor(v, 1);
      v += __shfl_xor(v, 2);
      v += __shfl_xor(v, 4);
      v += __shfl_xor(v, 8);
      lsum[r] = lsum[r] * corr[r] + v;
    }
#pragma unroll
    for (int i = 0; i < 8; i++)
#pragma unroll
      for (int r = 0; r < 4; r++) acc[i][r] *= corr[r];

    // ---- P -> LDS (permuted columns matching V positions) ----
    u16* pw = &Pl[w * 16 * 72];
#pragma unroll
    for (int t = 0; t < 4; t++){
      int pos = ((t >> 1) << 5) + 2*lr + (t & 1);
#pragma unroll
      for (int r = 0; r < 4; r++)
        pw[(lg*4 + r) * 72 + pos] = f2bf(s[t][r]);
    }
    s16x8 pf[2];
#pragma unroll
    for (int kk = 0; kk < 2; kk++)
      pf[kk] = *(const s16x8*)(pw + lr*72 + kk*32 + lg*8);

    // ---- PV : acc[8 hd-tiles] ----
#pragma unroll
    for (int t = 0; t < 8; t++){
      int col = t*16 + lr;
      const u32* vp = &Vts[col * 32];
#pragma unroll
      for (int kk = 0; kk < 2; kk++){
        s16x8 vf = *(const s16x8*)(vp + ((16*kk + 4*lg) ^ ((col & 7) << 2)));
        acc[t] = MFMA16(pf[kk], vf, acc[t]);
      }
    }
    __syncthreads();
  }

  // ---- epilogue: unnormalized partial O (fp32) + (m, l) per row ----
  float* pbase = opart + (size_t)blockIdx.x * (Qq * HDd);
#pragma unroll
  for (int t = 0; t < 8; t++){
#pragma unroll
    for (int r = 0; r < 4; r++){
      int qi = w*16 + lg*4 + r;
      pbase[(size_t)qi * HDd + t*16 + lr] = acc[t][r];
    }
  }
  if (lr == 0){
#pragma unroll
    for (int r = 0; r < 4; r++){
      int qi = w*16 + lg*4 + r;
      ml[(size_t)blockIdx.x * Qq + qi] = make_float2(mrow[r], lsum[r]);
    }
  }
}

// ---------------- combine split-KV partials ----------------
// grid = B*H*4 = 512 blocks, 256 threads; each block: 32 q-rows of one head.
__global__ __launch_bounds__(256)
void k_comb(const float* __restrict__ opart, const float2* __restrict__ ml,
            u16* __restrict__ ao)
{
  const int bh = blockIdx.x >> 2;
  const int q0 = (blockIdx.x & 3) * 32;
  const int tid = threadIdx.x;

  __shared__ float wgt[32][NSPLIT];
  __shared__ float Ls[32];

  {
    int row = tid >> 3, s = tid & 7;
    float2 v = ml[((size_t)(bh * NSPLIT + s)) * Qq + q0 + row];
    float m = v.x;
    m = fmaxf(m, __shfl_xor(m, 1));
    m = fmaxf(m, __shfl_xor(m, 2));
    m = fmaxf(m, __shfl_xor(m, 4));
    float e = __expf(v.x - m);
    float el = e * v.y;
    el += __shfl_xor(el, 1);
    el += __shfl_xor(el, 2);
    el += __shfl_xor(el, 4);
    wgt[row][s] = e;
    if (s == 0) Ls[row] = el;
  }
  __syncthreads();

  const int cp = tid & 63;        // column pair (0..63)
  const int r4 = tid >> 6;        // 0..3
  const int b = bh >> 4, h = bh & 15;
#pragma unroll
  for (int rr = 0; rr < 8; rr++){
    int row = r4 + rr*4;
    float2 a = make_float2(0.f, 0.f);
    const float* pb = opart + ((size_t)(bh * NSPLIT)) * (Qq * HDd)
                            + (size_t)(q0 + row) * HDd + cp*2;
#pragma unroll
    for (int s = 0; s < NSPLIT; s++){
      float2 p = *(const float2*)(pb + (size_t)s * (Qq * HDd));
      float wv = wgt[row][s];
      a.x += wv * p.x;
      a.y += wv * p.y;
    }
    float inv = 1.0f / Ls[row];
    u16* dst = ao + ((size_t)b * Qq + q0 + row) * Dd + h * HDd + cp*2;
    *(u32*)dst = pk2(a.x * inv, a.y * inv);
  }
}

extern "C" void kernel_launch(void* const* d_in, const int* in_sizes, int n_in,
                              void* d_out, int out_size, void* d_ws, size_t ws_size,
                              hipStream_t stream)
{
  const float* x     = (const float*)d_in[0];
  const float* kc    = (const float*)d_in[1];
  const float* vc    = (const float*)d_in[2];
  const float* wqkv  = (const float*)d_in[3];
  const float* wproj = (const float*)d_in[4];
  const float* bproj = (const float*)d_in[5];
  float* out = (float*)d_out;

  char* ws = (char*)d_ws;
  u16* xb  = (u16*)(ws);                      // 4 MB : x bf16 [1024][2048]
  u16* wtq = (u16*)(ws + ((size_t)4  << 20)); // 24 MB: Wqkv^T bf16 [6144][2048]
  u16* wtp = (u16*)(ws + ((size_t)28 << 20)); // 8 MB : Wproj^T bf16 [2048][2048]
  u16* qw  = (u16*)(ws + ((size_t)36 << 20)); // 4 MB : q (scaled) [B][H][Q][HD]
  u16* knw = (u16*)(ws + ((size_t)40 << 20)); // 4 MB : k_new
  u16* vnw = (u16*)(ws + ((size_t)44 << 20)); // 4 MB : v_new
  u16* aow = (u16*)(ws + ((size_t)48 << 20)); // 4 MB : attn out [1024][2048]
  float* opart = (float*)(ws + ((size_t)52 << 20));  // 64 MB: partial O fp32
  float2* mlw  = (float2*)(ws + ((size_t)116 << 20));// 1 MB : (m,l) per row

  k_cvt<<<2048, 256, 0, stream>>>(x, xb, (1024 * 2048) / 4);
  k_tcvt<<<dim3(192, 64), 256, 0, stream>>>(wqkv, wtq, 2048, 6144);
  k_tcvt<<<dim3(64, 64), 256, 0, stream>>>(wproj, wtp, 2048, 2048);
  k_gemm<0><<<dim3(48, 8), 256, 0, stream>>>(xb, wtq, 2048, 6144,
                                             qw, knw, vnw, nullptr, nullptr);
  k_attn<<<Bb * Hh * NSPLIT, 512, 0, stream>>>(kc, vc, qw, knw, vnw, opart, mlw);
  k_comb<<<Bb * Hh * 4, 256, 0, stream>>>(opart, mlw, aow);
  k_gemm<1><<<dim3(16, 8), 256, 0, stream>>>(aow, wtp, 2048, 2048,
                                             nullptr, nullptr, nullptr, out, bproj);
}